// Round 3
// baseline (512.465 us; speedup 1.0000x reference)
//
#include <hip/hip_runtime.h>
#include <cstdint>
#include <cstddef>

// Problem constants
#define B_   4
#define C_   2048      // seq / conv channels
#define DM_  128       // d_model / conv length
#define H_   8
#define KK_  14336     // C_ * 7  (im2col K dimension)
#define N_   512       // B_ * DM_ (GEMM N dimension)

#define KSPLIT 8
#define KPB   1792     // KK_ / KSPLIT
#define NITER 56       // KPB / 32
#define YSZ   ((size_t)B_ * C_ * DM_)   // one Y partial: 1,048,576 floats = 4 MB

typedef unsigned short u16;
typedef __attribute__((ext_vector_type(8))) short  s16x8;   // 8 x bf16 (4 VGPRs)
typedef __attribute__((ext_vector_type(4))) float  f32x4;

typedef const __attribute__((address_space(1))) void gvoid;
typedef __attribute__((address_space(3))) void lvoid;

__device__ __forceinline__ void gl2lds16(const void* g, void* l) {
    __builtin_amdgcn_global_load_lds((gvoid*)g, (lvoid*)l, 16, 0, 0);
}

// asm global load: keeps vmem issue order/count exact for manual s_waitcnt vmcnt(N)
__device__ __forceinline__ void gload4(float4& d, const float* p) {
    asm volatile("global_load_dwordx4 %0, %1, off" : "=v"(d) : "v"(p) : "memory");
}

__device__ __forceinline__ u16 f2bf(float f) {
    uint32_t u = __builtin_bit_cast(uint32_t, f);
    u += 0x7fffu + ((u >> 16) & 1u);   // round-to-nearest-even
    return (u16)(u >> 16);
}
__device__ __forceinline__ uint32_t pk2(float a, float b) {
    return (uint32_t)f2bf(a) | ((uint32_t)f2bf(b) << 16);
}

// ---------------------------------------------------------------- im2col^T prep
// BimT[n][k] = x[b][ci][l + t - 6] (0 if <0), n = b*128+l, k = ci*7+t, bf16.
__global__ __launch_bounds__(256) void prep_bimt(const float* __restrict__ key,
                                                 const float* __restrict__ value,
                                                 u16* __restrict__ bk,
                                                 u16* __restrict__ bv) {
    const float* src = blockIdx.z ? value : key;
    u16*         dst = blockIdx.z ? bv : bk;
    int gid = blockIdx.x * 256 + threadIdx.x;   // 0 .. 524287
    int cp = gid & 1023;                        // ci pair index
    int n  = gid >> 10;                         // 0 .. 511
    int b = n >> 7, l = n & 127;
    const float* s0 = src + (size_t)(b * C_ + cp * 2) * DM_;
    u16 hh[14];
#pragma unroll
    for (int r = 0; r < 2; ++r) {
#pragma unroll
        for (int t = 0; t < 7; ++t) {
            int j = l + t - 6;
            float v = (j >= 0) ? s0[r * DM_ + j] : 0.0f;
            hh[r * 7 + t] = f2bf(v);
        }
    }
    uint32_t* D = (uint32_t*)dst + (size_t)n * (KK_ / 2) + cp * 7;
#pragma unroll
    for (int i = 0; i < 7; ++i)
        D[i] = (uint32_t)hh[2 * i] | ((uint32_t)hh[2 * i + 1] << 16);
}

// ---------------------------------------------------------------- query prep (scale 1/4, bf16)
__global__ __launch_bounds__(256) void prep_q(const float4* __restrict__ q, uint2* __restrict__ qb) {
    int i = blockIdx.x * 256 + threadIdx.x;     // 0 .. 262143
    float4 v = q[i];
    uint2 r;
    r.x = pk2(v.x * 0.25f, v.y * 0.25f);
    r.y = pk2(v.z * 0.25f, v.w * 0.25f);
    qb[i] = r;
}

// ---------------------------------------------------------------- conv as GEMM
// Y[m=co][n=(b,l)] += sum_k W[m][k] * BimT[n][k]. splitK=8.
// v4: tile 128M x 128N for occupancy — grid 16x4x16 = 1024 blocks = 4/CU,
// LDS 40 KB (A 2x8 + B 3x8) -> 4x40 = 160 KiB exactly; acc 4x4 (64 VGPR).
// Counted-vmcnt pipeline kept: 3-deep B (global_load_lds, lead-2, 2 ops/group),
// 2-deep A (asm-loaded W regs -> VALU bf16 repack -> ds_write, lead-1, 4 ops).
// Loop wait: [B(t+1)2, W(t+1)4, B(t+2)2] -> vmcnt(2). Barrier crossed with 6.
// grid: x=16 Mtiles, y=4 Ntiles, z=16 (conv*8 + splitk)
__global__ __launch_bounds__(256, 4) void conv_gemm(
        const float* __restrict__ Wk, const float* __restrict__ Wv,
        const u16* __restrict__ Bk, const u16* __restrict__ Bv,
        float* __restrict__ Ypk, float* __restrict__ Ypv) {
    const int conv = blockIdx.z >> 3;
    const int sk   = blockIdx.z & 7;
    const float* W  = conv ? Wv : Wk;
    const u16*   Bm = conv ? Bv : Bk;
    float*       Yp = (conv ? Ypv : Ypk) + (size_t)sk * YSZ;
    const int m0 = blockIdx.x * 128;
    const int n0 = blockIdx.y * 128;
    const int kbeg = sk * KPB;

    __shared__ __align__(16) u16 Al[2][128 * 32];   // 8 KB each, rows 64 B, XOR-swizzled segs
    __shared__ __align__(16) u16 Bl[3][128 * 32];   // 8 KB each (24 KB; total LDS = 40 KB)

    const int tid = threadIdx.x;
    const int wave = tid >> 6, lane = tid & 63;
    const int l16 = lane & 15, quad = lane >> 4;
    const int wm = wave >> 1, wn = wave & 1;        // wave tile: 64M x 64N

    // ---- A (W) staging: thread covers 64 B (16 fp32) of one row
    const int arow = tid >> 1, ahalf = tid & 1;
    const float* wp = W + (size_t)(m0 + arow) * KK_ + kbeg + ahalf * 16;
    const int asw = (arow >> 1) & 3;
    const int aoff0 = arow * 32 + (((ahalf * 2)     ^ asw) * 8);
    const int aoff1 = arow * 32 + (((ahalf * 2 + 1) ^ asw) * 8);

    // ---- B staging via global_load_lds (2 passes/wave, 16 rows each)
    const u16* bgp[2];
    int boff[2];
    {
        const int br = lane >> 2, bs = lane & 3;
#pragma unroll
        for (int p = 0; p < 2; ++p) {
            int row = wave * 32 + p * 16 + br;
            int gc = (bs ^ ((row >> 1) & 3)) * 8;      // swizzled source chunk
            bgp[p] = Bm + (size_t)(n0 + row) * KK_ + kbeg + gc;
            boff[p] = (wave * 32 + p * 16) * 32;
        }
    }

    f32x4 acc[4][4];
#pragma unroll
    for (int i = 0; i < 4; ++i)
#pragma unroll
        for (int j = 0; j < 4; ++j) acc[i][j] = (f32x4){0.f, 0.f, 0.f, 0.f};

    float4 wr0, wr1, wr2, wr3;
    // ---- prologue: issue [B0][W0][B1][W1]; wait first 6; repack A0; publish.
    {
#pragma unroll
        for (int p = 0; p < 2; ++p)
            gl2lds16(bgp[p], &Bl[0][boff[p]]);
        float4 a0, a1, a2, a3;
        gload4(a0, wp);      gload4(a1, wp + 4);
        gload4(a2, wp + 8);  gload4(a3, wp + 12);
#pragma unroll
        for (int p = 0; p < 2; ++p)
            gl2lds16(bgp[p] + 32, &Bl[1][boff[p]]);
        gload4(wr0, wp + 32); gload4(wr1, wp + 36);
        gload4(wr2, wp + 40); gload4(wr3, wp + 44);
        asm volatile("s_waitcnt vmcnt(6)" ::: "memory");   // B0, W0 landed
        __builtin_amdgcn_sched_barrier(0);
        uint4 p0, p1;
        p0.x = pk2(a0.x, a0.y); p0.y = pk2(a0.z, a0.w);
        p0.z = pk2(a1.x, a1.y); p0.w = pk2(a1.z, a1.w);
        p1.x = pk2(a2.x, a2.y); p1.y = pk2(a2.z, a2.w);
        p1.z = pk2(a3.x, a3.y); p1.w = pk2(a3.z, a3.w);
        *(uint4*)&Al[0][aoff0] = p0;
        *(uint4*)&Al[0][aoff1] = p1;
        asm volatile("s_waitcnt lgkmcnt(0)" ::: "memory");
        __builtin_amdgcn_sched_barrier(0);
        __builtin_amdgcn_s_barrier();                      // crossing with 6 vmem in flight
    }

    int bcur = 0;                                          // t % 3
    for (int t = 0; t < NITER; ++t) {
        const int ap = t & 1;
        int bst = bcur - 1; if (bst < 0) bst = 2;          // (t+2) % 3
        const int kb = (t + 2 < NITER) ? t + 2 : NITER - 1;

        // a: frag reads from published buffers (tile t)
        s16x8 af[4];
#pragma unroll
        for (int fm = 0; fm < 4; ++fm) {
            int r = wm * 64 + fm * 16 + l16;
            af[fm] = *(const s16x8*)&Al[ap][r * 32 + ((quad ^ ((r >> 1) & 3)) * 8)];
        }
        s16x8 bfr[4];
#pragma unroll
        for (int fn = 0; fn < 4; ++fn) {
            int n = wn * 64 + fn * 16 + l16;
            bfr[fn] = *(const s16x8*)&Bl[bcur][n * 32 + ((quad ^ ((n >> 1) & 3)) * 8)];
        }
        // b: stage B(t+2) into Bl[(t+2)%3] (that buffer was read at t-1)
#pragma unroll
        for (int p = 0; p < 2; ++p)
            gl2lds16(bgp[p] + (size_t)kb * 32, &Bl[bst][boff[p]]);
        // c: MFMA 4x4
#pragma unroll
        for (int fm = 0; fm < 4; ++fm)
#pragma unroll
            for (int fn = 0; fn < 4; ++fn)
                acc[fm][fn] = __builtin_amdgcn_mfma_f32_16x16x32_bf16(af[fm], bfr[fn], acc[fm][fn], 0, 0, 0);

        // f: counted wait -> W(t+1) (for repack) and B(t+1) (published at barrier)
        asm volatile("s_waitcnt vmcnt(2)" ::: "memory");
        __builtin_amdgcn_sched_barrier(0);

        // g: repack A(t+1) -> Al[(t+1)&1]
        {
            uint4 q0, q1;
            q0.x = pk2(wr0.x, wr0.y); q0.y = pk2(wr0.z, wr0.w);
            q0.z = pk2(wr1.x, wr1.y); q0.w = pk2(wr1.z, wr1.w);
            q1.x = pk2(wr2.x, wr2.y); q1.y = pk2(wr2.z, wr2.w);
            q1.z = pk2(wr3.x, wr3.y); q1.w = pk2(wr3.z, wr3.w);
            *(uint4*)&Al[ap ^ 1][aoff0] = q0;
            *(uint4*)&Al[ap ^ 1][aoff1] = q1;
        }
        // h: issue W(t+2) reload (consumed at iter t+1's repack)
        gload4(wr0, wp + (size_t)kb * 32);
        gload4(wr1, wp + (size_t)kb * 32 + 4);
        gload4(wr2, wp + (size_t)kb * 32 + 8);
        gload4(wr3, wp + (size_t)kb * 32 + 12);

        // i/j: drain LDS ops (A writes + frag reads) and publish tile t+1.
        // vmcnt NOT drained: B(t+2), W(t+2) (6 ops) cross the barrier in flight.
        asm volatile("s_waitcnt lgkmcnt(0)" ::: "memory");
        __builtin_amdgcn_sched_barrier(0);
        __builtin_amdgcn_s_barrier();

        bcur = (bcur == 2) ? 0 : bcur + 1;
    }
    // drain in-flight LDS-DMA before workgroup teardown
    asm volatile("s_waitcnt vmcnt(0)" ::: "memory");
    __builtin_amdgcn_sched_barrier(0);

    // epilogue: plain stores to this block's private split-K partial.
    // C layout: col = lane&15, row = quad*4 + reg. Each element written once.
#pragma unroll
    for (int fm = 0; fm < 4; ++fm) {
        int m = m0 + wm * 64 + fm * 16 + quad * 4;
#pragma unroll
        for (int fn = 0; fn < 4; ++fn) {
            int n = n0 + wn * 64 + fn * 16 + l16;
            int bb = n >> 7, ll = n & 127;
            float* yp = Yp + ((size_t)(bb * C_ + m)) * DM_ + ll;
#pragma unroll
            for (int r = 0; r < 4; ++r)
                yp[(size_t)r * DM_] = acc[fm][fn][r];
        }
    }
}

// ---------------------------------------------------------------- K/V prep for attention
// Sums 8 split-K partials, adds bias, emits bf16:
// Kbf[bh][key][d16] ; Vbf[bh][d16][key] (transposed).
__global__ __launch_bounds__(256) void kv_prep(
        const float* __restrict__ Ypk, const float* __restrict__ Ypv,
        const float* __restrict__ bkb, const float* __restrict__ bvb,
        u16* __restrict__ Kbf, u16* __restrict__ Vbf) {
    int gid = blockIdx.x * 256 + threadIdx.x;   // 0 .. 65535
    int key = gid & 2047;
    int bh  = gid >> 11;
    int b = bh >> 3, h = bh & 7;
    size_t src = ((size_t)(b * C_ + key)) * DM_ + h * 16;
    float kb = bkb[key], vb = bvb[key];

    float ka[16] = {0.f, 0.f, 0.f, 0.f, 0.f, 0.f, 0.f, 0.f,
                    0.f, 0.f, 0.f, 0.f, 0.f, 0.f, 0.f, 0.f};
    float va[16] = {0.f, 0.f, 0.f, 0.f, 0.f, 0.f, 0.f, 0.f,
                    0.f, 0.f, 0.f, 0.f, 0.f, 0.f, 0.f, 0.f};
#pragma unroll
    for (int sk = 0; sk < KSPLIT; ++sk) {
        const float* pk = Ypk + (size_t)sk * YSZ + src;
        const float* pv = Ypv + (size_t)sk * YSZ + src;
#pragma unroll
        for (int c = 0; c < 4; ++c) {
            float4 fk = *(const float4*)(pk + c * 4);
            float4 fv = *(const float4*)(pv + c * 4);
            ka[c * 4 + 0] += fk.x; ka[c * 4 + 1] += fk.y;
            ka[c * 4 + 2] += fk.z; ka[c * 4 + 3] += fk.w;
            va[c * 4 + 0] += fv.x; va[c * 4 + 1] += fv.y;
            va[c * 4 + 2] += fv.z; va[c * 4 + 3] += fv.w;
        }
    }

    uint4 pA, pB;
    pA.x = pk2(ka[0] + kb, ka[1] + kb);  pA.y = pk2(ka[2] + kb, ka[3] + kb);
    pA.z = pk2(ka[4] + kb, ka[5] + kb);  pA.w = pk2(ka[6] + kb, ka[7] + kb);
    pB.x = pk2(ka[8] + kb, ka[9] + kb);  pB.y = pk2(ka[10] + kb, ka[11] + kb);
    pB.z = pk2(ka[12] + kb, ka[13] + kb); pB.w = pk2(ka[14] + kb, ka[15] + kb);
    u16* kd = Kbf + ((size_t)bh * C_ + key) * 16;
    *(uint4*)kd       = pA;
    *(uint4*)(kd + 8) = pB;

    u16* vdst = Vbf + (size_t)bh * 16 * C_ + key;
#pragma unroll
    for (int d = 0; d < 16; ++d)
        vdst[(size_t)d * C_] = f2bf(va[d] + vb);   // coalesced across lanes (key fastest)
}

// ---------------------------------------------------------------- flash attention
// grid: x = 32 q-tiles (64 rows), y = 32 (b*8+h). Block 256 = 4 waves; wave owns 16 q-rows.
__global__ __launch_bounds__(256, 4) void attn_k(
        const u16* __restrict__ Kbf, const u16* __restrict__ Vbf,
        const u16* __restrict__ qb, u16* __restrict__ att) {
    const int q0 = blockIdx.x * 64;
    const int bh = blockIdx.y;
    const int b = bh >> 3, h = bh & 7;

    __shared__ __align__(16) u16 Kl[128 * 24];   // key rows x 16 d, padded to 48 B
    __shared__ __align__(16) u16 Vl[16 * 128];   // d rows x 128 keys, chunk-swizzled
    __shared__ __align__(16) u16 Pl[64 * 136];   // q rows x 128 keys

    const int tid = threadIdx.x;
    const int wave = tid >> 6, lane = tid & 63;
    const int l16 = lane & 15, quad = lane >> 4;
    const float LOG2E = 1.44269504088896340736f;

    // K staging (manual, padded rows): thread covers 16 B of one key row
    const u16* kgp = Kbf + ((size_t)bh * C_ + (tid >> 1)) * 16 + (tid & 1) * 8;
    u16* kld = &Kl[(tid >> 1) * 24 + (tid & 1) * 8];
    // V staging via global_load_lds: lane: d = wave*4 + (lane>>4), chunk = lane&15 (swizzled source)
    const int vd = wave * 4 + (lane >> 4);
    const u16* vgp = Vbf + ((size_t)bh * 16 + vd) * C_ + (size_t)(((lane & 15) ^ (vd & 7)) * 8);
    u16* vld = &Vl[wave * 4 * 128];

    // Q fragment (A-layout): m = lane&15, k(d) = quad*8+j ; d>=16 zero padding.
    s16x8 qf = {};
    if (quad < 2) {
        const u16* qp = qb + ((size_t)(b * C_ + q0 + wave * 16 + l16)) * DM_ + h * 16 + quad * 8;
        qf = *(const s16x8*)qp;
    }
    f32x4 o = (f32x4){0.f, 0.f, 0.f, 0.f};
    float mr[4] = {-3e38f, -3e38f, -3e38f, -3e38f};
    float lr[4] = {0.f, 0.f, 0.f, 0.f};

    for (int kt = 0; kt < 16; ++kt) {
        const int k0 = kt * 128;
        __syncthreads();                       // prev PV reads of Vl done
        {
            uint4 kv = *(const uint4*)(kgp + (size_t)k0 * 16);
            *(uint4*)kld = kv;
            gl2lds16(vgp + k0, vld);
        }
        __syncthreads();                       // K/V staged (drains LDS-DMA too)

        // S = Q K^T : 8 N-frags of 16 keys
        f32x4 sf[8];
#pragma unroll
        for (int fn = 0; fn < 8; ++fn) {
            s16x8 kb = {};
            if (quad < 2) kb = *(const s16x8*)&Kl[(fn * 16 + l16) * 24 + quad * 8];
            sf[fn] = __builtin_amdgcn_mfma_f32_16x16x32_bf16(qf, kb, (f32x4){0.f, 0.f, 0.f, 0.f}, 0, 0, 0);
        }

        // online softmax: lane holds rows quad*4+r, cols l16 + 16*fn
        float mt[4];
#pragma unroll
        for (int r = 0; r < 4; ++r) {
            float m = sf[0][r];
#pragma unroll
            for (int fn = 1; fn < 8; ++fn) m = fmaxf(m, sf[fn][r]);
            m = fmaxf(m, __shfl_xor(m, 1));
            m = fmaxf(m, __shfl_xor(m, 2));
            m = fmaxf(m, __shfl_xor(m, 4));
            m = fmaxf(m, __shfl_xor(m, 8));
            mt[r] = m;
        }
        float al[4], ps[4];
#pragma unroll
        for (int r = 0; r < 4; ++r) {
            float mnew = fmaxf(mr[r], mt[r]);
            al[r] = exp2f((mr[r] - mnew) * LOG2E);
            mr[r] = mnew;
            ps[r] = 0.f;
        }
#pragma unroll
        for (int fn = 0; fn < 8; ++fn) {
#pragma unroll
            for (int r = 0; r < 4; ++r) {
                float p = exp2f((sf[fn][r] - mr[r]) * LOG2E);
                ps[r] += p;
                Pl[(wave * 16 + quad * 4 + r) * 136 + fn * 16 + l16] = f2bf(p);
            }
        }
#pragma unroll
        for (int r = 0; r < 4; ++r) {
            float t = ps[r];
            t += __shfl_xor(t, 1);
            t += __shfl_xor(t, 2);
            t += __shfl_xor(t, 4);
            t += __shfl_xor(t, 8);
            lr[r] = lr[r] * al[r] + t;
            o[r] *= al[r];
        }
        // Pl region is wave-private: same-wave ds_write -> ds_read needs no barrier.
        // O += P V  (K-dim = 128 keys, 4 MFMAs)
#pragma unroll
        for (int ko = 0; ko < 4; ++ko) {
            s16x8 pa = *(const s16x8*)&Pl[(wave * 16 + l16) * 136 + ko * 32 + quad * 8];
            s16x8 vb = *(const s16x8*)&Vl[l16 * 128 + (((ko * 4 + quad) ^ (l16 & 7)) * 8)];
            o = __builtin_amdgcn_mfma_f32_16x16x32_bf16(pa, vb, o, 0, 0, 0);
        }
    }

#pragma unroll
    for (int r = 0; r < 4; ++r) {
        float inv = 1.0f / lr[r];
        int row = q0 + wave * 16 + quad * 4 + r;
        att[((size_t)(b * C_ + row)) * DM_ + h * 16 + l16] = f2bf(o[r] * inv);
    }
}

// ---------------------------------------------------------------- final linear: out = att @ lw^T + lb
__global__ __launch_bounds__(256, 2) void lin_k(
        const u16* __restrict__ att, const float* __restrict__ lw,
        const float* __restrict__ lb, float* __restrict__ out) {
    const int r0 = blockIdx.x * 32;
    __shared__ __align__(16) u16 Wl[128 * 136];
    __shared__ __align__(16) u16 Atl[32 * 136];
    const int tid = threadIdx.x;
    const int wave = tid >> 6, lane = tid & 63;
    const int l16 = lane & 15, quad = lane >> 4;

    {   // stage lin_w -> bf16, layout Wl[j][i]
        int j = tid >> 1, half = tid & 1;
        const float* src = lw + (size_t)j * DM_ + half * 64;
        u16* dstp = &Wl[j * 136 + half * 64];
#pragma unroll
        for (int c = 0; c < 8; ++c) {
            float4 f0 = *(const float4*)(src + c * 8);
            float4 f1 = *(const float4*)(src + c * 8 + 4);
            uint4 p;
            p.x = pk2(f0.x, f0.y); p.y = pk2(f0.z, f0.w);
            p.z = pk2(f1.x, f1.y); p.w = pk2(f1.z, f1.w);
            *(uint4*)(dstp + c * 8) = p;
        }
    }
    {   // stage att tile
        int row = tid >> 3, seg = tid & 7;
        const uint4* src = (const uint4*)(att + ((size_t)(r0 + row)) * DM_ + seg * 16);
        uint4 a0 = src[0], a1 = src[1];
        *(uint4*)&Atl[row * 136 + seg * 16]     = a0;
        *(uint4*)&Atl[row * 136 + seg * 16 + 8] = a1;
    }
    __syncthreads();

    const int wn0 = wave * 32;
    f32x4 acc[2][2];
#pragma unroll
    for (int i = 0; i < 2; ++i)
#pragma unroll
        for (int j = 0; j < 2; ++j) acc[i][j] = (f32x4){0.f, 0.f, 0.f, 0.f};
#pragma unroll
    for (int ko = 0; ko < 4; ++ko) {
        s16x8 af[2], bf[2];
#pragma unroll
        for (int fm = 0; fm < 2; ++fm)
            af[fm] = *(const s16x8*)&Atl[(fm * 16 + l16) * 136 + ko * 32 + quad * 8];
#pragma unroll
        for (int fn = 0; fn < 2; ++fn)
            bf[fn] = *(const s16x8*)&Wl[(wn0 + fn * 16 + l16) * 136 + ko * 32 + quad * 8];
#pragma unroll
        for (int fm = 0; fm < 2; ++fm)
#pragma unroll
            for (int fn = 0; fn < 2; ++fn)
                acc[fm][fn] = __builtin_amdgcn_mfma_f32_16x16x32_bf16(af[fm], bf[fn], acc[fm][fn], 0, 0, 0);
    }
#pragma unroll
    for (int fm = 0; fm < 2; ++fm) {
#pragma unroll
        for (int fn = 0; fn < 2; ++fn) {
            int col = wn0 + fn * 16 + l16;
            float bias = lb[col];
#pragma unroll
            for (int r = 0; r < 4; ++r) {
                int row = r0 + fm * 16 + quad * 4 + r;
                out[(size_t)row * DM_ + col] = acc[fm][fn][r] + bias;
            }
        }
    }
}

// ---------------------------------------------------------------- launcher
extern "C" void kernel_launch(void* const* d_in, const int* in_sizes, int n_in,
                              void* d_out, int out_size, void* d_ws, size_t ws_size,
                              hipStream_t stream) {
    const float* query = (const float*)d_in[0];
    const float* key   = (const float*)d_in[1];
    const float* value = (const float*)d_in[2];
    const float* wk    = (const float*)d_in[3];
    const float* bk    = (const float*)d_in[4];
    const float* wv    = (const float*)d_in[5];
    const float* bv    = (const float*)d_in[6];
    const float* lw    = (const float*)d_in[7];
    const float* lb    = (const float*)d_in[8];
    float* out = (float*)d_out;

    char* ws = (char*)d_ws;
    u16*   bimt_k = (u16*)(ws);                       // 14,680,064 B
    u16*   bimt_v = (u16*)(ws + 14680064);            // 14,680,064 B (end 29,360,128)
    u16*   qbf    = (u16*)(ws + 29360128);            // 2 MB
    u16*   att    = (u16*)(ws + 31457280);            // 2 MB
    u16*   kbf    = (u16*)(ws + 33554432);            // 2 MB
    u16*   vbf    = (u16*)(ws + 35651584);            // 2 MB (end 37,748,736)
    float* ypk    = (float*)(ws + 37748736);          // 8 x 4 MB = 32 MB
    float* ypv    = (float*)(ws + 71303168);          // 8 x 4 MB = 32 MB (end ~100 MB)

    // 1) im2col^T bf16 for key & value
    prep_bimt<<<dim3(2048, 1, 2), 256, 0, stream>>>(key, value, bimt_k, bimt_v);
    // 2) query -> bf16 * 0.25
    prep_q<<<1024, 256, 0, stream>>>((const float4*)query, (uint2*)qbf);
    // 3) both convs as split-K GEMM -> private fp32 partials (no atomics, no zero-init)
    conv_gemm<<<dim3(16, 4, 16), 256, 0, stream>>>(wk, wv, bimt_k, bimt_v, ypk, ypv);
    // 4) sum partials + bias + bf16 + transpose prep for attention K/V
    kv_prep<<<256, 256, 0, stream>>>(ypk, ypv, bk, bv, kbf, vbf);
    // 5) flash attention
    attn_k<<<dim3(32, 32), 256, 0, stream>>>(kbf, vbf, qbf, att);
    // 6) output projection
    lin_k<<<256, 256, 0, stream>>>(att, lw, lb, out);
}

// Round 4
// 452.995 us; speedup vs baseline: 1.1313x; 1.1313x over previous
//
#include <hip/hip_runtime.h>
#include <cstdint>
#include <cstddef>

// Problem constants
#define B_   4
#define C_   2048      // seq / conv channels
#define DM_  128       // d_model / conv length
#define H_   8
#define KK_  14336     // C_ * 7  (im2col K dimension)
#define N_   512       // B_ * DM_ (GEMM N dimension)

#define KSPLIT 8
#define KPB   1792     // KK_ / KSPLIT
#define NITER 56       // KPB / 32
#define YSZ   ((size_t)B_ * C_ * DM_)   // one Y partial: 1,048,576 floats = 4 MB

typedef unsigned short u16;
typedef __attribute__((ext_vector_type(8))) short  s16x8;   // 8 x bf16 (4 VGPRs)
typedef __attribute__((ext_vector_type(4))) float  f32x4;

typedef const __attribute__((address_space(1))) void gvoid;
typedef __attribute__((address_space(3))) void lvoid;

__device__ __forceinline__ void gl2lds16(const void* g, void* l) {
    __builtin_amdgcn_global_load_lds((gvoid*)g, (lvoid*)l, 16, 0, 0);
}

// asm global load: keeps vmem issue order/count exact for manual s_waitcnt vmcnt(N)
__device__ __forceinline__ void gload4(float4& d, const float* p) {
    asm volatile("global_load_dwordx4 %0, %1, off" : "=v"(d) : "v"(p) : "memory");
}

// raw v_exp_f32 (2^x) — avoids ocml exp2f call overhead; VALU interlocks handle deps
__device__ __forceinline__ float fexp2(float x) {
    float r;
    asm("v_exp_f32 %0, %1" : "=v"(r) : "v"(x));
    return r;
}

__device__ __forceinline__ u16 f2bf(float f) {
    uint32_t u = __builtin_bit_cast(uint32_t, f);
    u += 0x7fffu + ((u >> 16) & 1u);   // round-to-nearest-even
    return (u16)(u >> 16);
}
__device__ __forceinline__ uint32_t pk2(float a, float b) {
    return (uint32_t)f2bf(a) | ((uint32_t)f2bf(b) << 16);
}

// ---------------------------------------------------------------- im2col^T prep
// BimT[n][k] = x[b][ci][l + t - 6] (0 if <0), n = b*128+l, k = ci*7+t, bf16.
__global__ __launch_bounds__(256) void prep_bimt(const float* __restrict__ key,
                                                 const float* __restrict__ value,
                                                 u16* __restrict__ bk,
                                                 u16* __restrict__ bv) {
    const float* src = blockIdx.z ? value : key;
    u16*         dst = blockIdx.z ? bv : bk;
    int gid = blockIdx.x * 256 + threadIdx.x;   // 0 .. 524287
    int cp = gid & 1023;                        // ci pair index
    int n  = gid >> 10;                         // 0 .. 511
    int b = n >> 7, l = n & 127;
    const float* s0 = src + (size_t)(b * C_ + cp * 2) * DM_;
    u16 hh[14];
#pragma unroll
    for (int r = 0; r < 2; ++r) {
#pragma unroll
        for (int t = 0; t < 7; ++t) {
            int j = l + t - 6;
            float v = (j >= 0) ? s0[r * DM_ + j] : 0.0f;
            hh[r * 7 + t] = f2bf(v);
        }
    }
    uint32_t* D = (uint32_t*)dst + (size_t)n * (KK_ / 2) + cp * 7;
#pragma unroll
    for (int i = 0; i < 7; ++i)
        D[i] = (uint32_t)hh[2 * i] | ((uint32_t)hh[2 * i + 1] << 16);
}

// ---------------------------------------------------------------- query prep (scale 1/4, bf16)
__global__ __launch_bounds__(256) void prep_q(const float4* __restrict__ q, uint2* __restrict__ qb) {
    int i = blockIdx.x * 256 + threadIdx.x;     // 0 .. 262143
    float4 v = q[i];
    uint2 r;
    r.x = pk2(v.x * 0.25f, v.y * 0.25f);
    r.y = pk2(v.z * 0.25f, v.w * 0.25f);
    qb[i] = r;
}

// ---------------------------------------------------------------- conv as GEMM
// Y[m=co][n=(b,l)] += sum_k W[m][k] * BimT[n][k]. Tile 128M x 256N, splitK=8.
// (exact round-2 config: 940 MB request traffic, 2 blocks/CU, 154 us measured)
// Counted-vmcnt pipeline (T3/T4): 3-deep B (global_load_lds, lead-2),
// 2-deep A (asm-loaded W regs -> VALU bf16 repack -> ds_write, lead-1).
// Split-K epilogue writes private fp32 partials; kv_prep sums the 8 partials.
// grid: x=16 Mtiles, y=2 Ntiles, z=16 (conv*8 + splitk)
__global__ __launch_bounds__(256, 2) void conv_gemm(
        const float* __restrict__ Wk, const float* __restrict__ Wv,
        const u16* __restrict__ Bk, const u16* __restrict__ Bv,
        float* __restrict__ Ypk, float* __restrict__ Ypv) {
    const int conv = blockIdx.z >> 3;
    const int sk   = blockIdx.z & 7;
    const float* W  = conv ? Wv : Wk;
    const u16*   Bm = conv ? Bv : Bk;
    float*       Yp = (conv ? Ypv : Ypk) + (size_t)sk * YSZ;
    const int m0 = blockIdx.x * 128;
    const int n0 = blockIdx.y * 256;
    const int kbeg = sk * KPB;

    __shared__ __align__(16) u16 Al[2][128 * 32];   // 8 KB each, rows 64 B, XOR-swizzled segs
    __shared__ __align__(16) u16 Bl[3][256 * 32];   // 16 KB each (48 KB; total LDS = 64 KB)

    const int tid = threadIdx.x;
    const int wave = tid >> 6, lane = tid & 63;
    const int l16 = lane & 15, quad = lane >> 4;
    const int wm = wave >> 1, wn = wave & 1;        // wave tile: 64M x 128N

    // ---- A (W) staging: thread covers 64 B (16 fp32) of one row
    const int arow = tid >> 1, ahalf = tid & 1;
    const float* wp = W + (size_t)(m0 + arow) * KK_ + kbeg + ahalf * 16;
    const int asw = (arow >> 1) & 3;
    const int aoff0 = arow * 32 + (((ahalf * 2)     ^ asw) * 8);
    const int aoff1 = arow * 32 + (((ahalf * 2 + 1) ^ asw) * 8);

    // ---- B staging via global_load_lds (4 passes/wave, 16 rows each)
    const u16* bgp[4];
    int boff[4];
    {
        const int br = lane >> 2, bs = lane & 3;
#pragma unroll
        for (int p = 0; p < 4; ++p) {
            int row = wave * 64 + p * 16 + br;
            int gc = (bs ^ ((row >> 1) & 3)) * 8;      // swizzled source chunk
            bgp[p] = Bm + (size_t)(n0 + row) * KK_ + kbeg + gc;
            boff[p] = (wave * 64 + p * 16) * 32;
        }
    }

    f32x4 acc[4][8];
#pragma unroll
    for (int i = 0; i < 4; ++i)
#pragma unroll
        for (int j = 0; j < 8; ++j) acc[i][j] = (f32x4){0.f, 0.f, 0.f, 0.f};

    float4 wr0, wr1, wr2, wr3;
    // ---- prologue: issue [B0][W0][B1][W1]; wait first 8; repack A0; publish.
    {
#pragma unroll
        for (int p = 0; p < 4; ++p)
            gl2lds16(bgp[p], &Bl[0][boff[p]]);
        float4 a0, a1, a2, a3;
        gload4(a0, wp);      gload4(a1, wp + 4);
        gload4(a2, wp + 8);  gload4(a3, wp + 12);
#pragma unroll
        for (int p = 0; p < 4; ++p)
            gl2lds16(bgp[p] + 32, &Bl[1][boff[p]]);
        gload4(wr0, wp + 32); gload4(wr1, wp + 36);
        gload4(wr2, wp + 40); gload4(wr3, wp + 44);
        asm volatile("s_waitcnt vmcnt(8)" ::: "memory");   // B0, W0 landed
        __builtin_amdgcn_sched_barrier(0);
        uint4 p0, p1;
        p0.x = pk2(a0.x, a0.y); p0.y = pk2(a0.z, a0.w);
        p0.z = pk2(a1.x, a1.y); p0.w = pk2(a1.z, a1.w);
        p1.x = pk2(a2.x, a2.y); p1.y = pk2(a2.z, a2.w);
        p1.z = pk2(a3.x, a3.y); p1.w = pk2(a3.z, a3.w);
        *(uint4*)&Al[0][aoff0] = p0;
        *(uint4*)&Al[0][aoff1] = p1;
        asm volatile("s_waitcnt lgkmcnt(0)" ::: "memory");
        __builtin_amdgcn_sched_barrier(0);
        __builtin_amdgcn_s_barrier();                      // crossing with 8 vmem in flight
    }

    int bcur = 0;                                          // t % 3
    for (int t = 0; t < NITER; ++t) {
        const int ap = t & 1;
        int bst = bcur - 1; if (bst < 0) bst = 2;          // (t+2) % 3
        const int kb = (t + 2 < NITER) ? t + 2 : NITER - 1;

        // a: frag reads from published buffers (tile t)
        s16x8 af[4];
#pragma unroll
        for (int fm = 0; fm < 4; ++fm) {
            int r = wm * 64 + fm * 16 + l16;
            af[fm] = *(const s16x8*)&Al[ap][r * 32 + ((quad ^ ((r >> 1) & 3)) * 8)];
        }
        s16x8 bfr[4];
#pragma unroll
        for (int fn = 0; fn < 4; ++fn) {
            int n = wn * 128 + fn * 16 + l16;
            bfr[fn] = *(const s16x8*)&Bl[bcur][n * 32 + ((quad ^ ((n >> 1) & 3)) * 8)];
        }
        // b: stage B(t+2) into Bl[(t+2)%3] (that buffer was read at t-1)
#pragma unroll
        for (int p = 0; p < 4; ++p)
            gl2lds16(bgp[p] + (size_t)kb * 32, &Bl[bst][boff[p]]);
        // c: MFMA first N-half
#pragma unroll
        for (int fm = 0; fm < 4; ++fm)
#pragma unroll
            for (int fn = 0; fn < 4; ++fn)
                acc[fm][fn] = __builtin_amdgcn_mfma_f32_16x16x32_bf16(af[fm], bfr[fn], acc[fm][fn], 0, 0, 0);
        // d: second N-half frags
#pragma unroll
        for (int fn = 0; fn < 4; ++fn) {
            int n = wn * 128 + (fn + 4) * 16 + l16;
            bfr[fn] = *(const s16x8*)&Bl[bcur][n * 32 + ((quad ^ ((n >> 1) & 3)) * 8)];
        }
        // e: MFMA second N-half
#pragma unroll
        for (int fm = 0; fm < 4; ++fm)
#pragma unroll
            for (int fn = 0; fn < 4; ++fn)
                acc[fm][fn + 4] = __builtin_amdgcn_mfma_f32_16x16x32_bf16(af[fm], bfr[fn], acc[fm][fn + 4], 0, 0, 0);

        // f: counted wait -> W(t+1) (for repack) and B(t+1) (published at barrier)
        asm volatile("s_waitcnt vmcnt(4)" ::: "memory");
        __builtin_amdgcn_sched_barrier(0);

        // g: repack A(t+1) -> Al[(t+1)&1]
        {
            uint4 q0, q1;
            q0.x = pk2(wr0.x, wr0.y); q0.y = pk2(wr0.z, wr0.w);
            q0.z = pk2(wr1.x, wr1.y); q0.w = pk2(wr1.z, wr1.w);
            q1.x = pk2(wr2.x, wr2.y); q1.y = pk2(wr2.z, wr2.w);
            q1.z = pk2(wr3.x, wr3.y); q1.w = pk2(wr3.z, wr3.w);
            *(uint4*)&Al[ap ^ 1][aoff0] = q0;
            *(uint4*)&Al[ap ^ 1][aoff1] = q1;
        }
        // h: issue W(t+2) reload (consumed at iter t+1's repack)
        gload4(wr0, wp + (size_t)kb * 32);
        gload4(wr1, wp + (size_t)kb * 32 + 4);
        gload4(wr2, wp + (size_t)kb * 32 + 8);
        gload4(wr3, wp + (size_t)kb * 32 + 12);

        // i/j: drain LDS ops (A writes + frag reads) and publish tile t+1.
        // vmcnt NOT drained: B(t+2), W(t+2) (8 ops) cross the barrier in flight.
        asm volatile("s_waitcnt lgkmcnt(0)" ::: "memory");
        __builtin_amdgcn_sched_barrier(0);
        __builtin_amdgcn_s_barrier();

        bcur = (bcur == 2) ? 0 : bcur + 1;
    }
    // drain in-flight LDS-DMA before workgroup teardown
    asm volatile("s_waitcnt vmcnt(0)" ::: "memory");
    __builtin_amdgcn_sched_barrier(0);

    // epilogue: plain stores to this block's private split-K partial.
    // C layout: col = lane&15, row = quad*4 + reg. Each element written once.
#pragma unroll
    for (int fm = 0; fm < 4; ++fm) {
        int m = m0 + wm * 64 + fm * 16 + quad * 4;
#pragma unroll
        for (int fn = 0; fn < 8; ++fn) {
            int n = n0 + wn * 128 + fn * 16 + l16;
            int bb = n >> 7, ll = n & 127;
            float* yp = Yp + ((size_t)(bb * C_ + m)) * DM_ + ll;
#pragma unroll
            for (int r = 0; r < 4; ++r)
                yp[(size_t)r * DM_] = acc[fm][fn][r];
        }
    }
}

// ---------------------------------------------------------------- K/V prep for attention
// v2: coalesced — half-wave (32 lanes) owns one (b,co) row of 128 floats.
// Sums 8 split-K partials (16 coalesced float4 streams), adds bias, emits bf16:
// Kbf[bh][key][d16] (coalesced 8B/lane) ; Vbf[bh][d16][key] (scatter stores).
// grid: 1024 blocks x 256 thr -> 8 rows/block, 8192 rows total.
__global__ __launch_bounds__(256) void kv_prep(
        const float* __restrict__ Ypk, const float* __restrict__ Ypv,
        const float* __restrict__ bkb, const float* __restrict__ bvb,
        u16* __restrict__ Kbf, u16* __restrict__ Vbf) {
    const int tid = threadIdx.x;
    const int rid = blockIdx.x * 8 + (tid >> 5);   // (b, co) row id, 0..8191
    const int lane32 = tid & 31;
    const int b = rid >> 11, key = rid & 2047;
    const int d0 = lane32 * 4;                     // l-offset within row, 0..124
    const size_t src = (size_t)rid * DM_ + d0;

    float kx = 0.f, ky = 0.f, kz = 0.f, kw = 0.f;
    float vx = 0.f, vy = 0.f, vz = 0.f, vw = 0.f;
#pragma unroll
    for (int sk = 0; sk < KSPLIT; ++sk) {
        float4 fk = *(const float4*)(Ypk + (size_t)sk * YSZ + src);
        float4 fv = *(const float4*)(Ypv + (size_t)sk * YSZ + src);
        kx += fk.x; ky += fk.y; kz += fk.z; kw += fk.w;
        vx += fv.x; vy += fv.y; vz += fv.z; vw += fv.w;
    }
    const float kb = bkb[key], vb = bvb[key];

    const int h = d0 >> 4, dd = d0 & 15;           // head, d-within-head
    uint2 kp;
    kp.x = pk2(kx + kb, ky + kb);
    kp.y = pk2(kz + kb, kw + kb);
    *(uint2*)(Kbf + (((size_t)(b * 8 + h) * C_ + key) * 16 + dd)) = kp;

    u16* vd = Vbf + ((size_t)(b * 8 + h) * 16 + dd) * C_ + key;
    vd[0]          = f2bf(vx + vb);
    vd[(size_t)C_]     = f2bf(vy + vb);
    vd[(size_t)C_ * 2] = f2bf(vz + vb);
    vd[(size_t)C_ * 3] = f2bf(vw + vb);
}

// ---------------------------------------------------------------- flash attention
// v2: lead-1 double-buffered K/V staging, ONE barrier per k-tile (stage latency
// hidden under softmax+PV), raw v_exp_f32.
// grid: x = 32 q-tiles (64 rows), y = 32 (b*8+h). Block 256 = 4 waves; wave owns 16 q-rows.
__global__ __launch_bounds__(256, 4) void attn_k(
        const u16* __restrict__ Kbf, const u16* __restrict__ Vbf,
        const u16* __restrict__ qb, u16* __restrict__ att) {
    const int q0 = blockIdx.x * 64;
    const int bh = blockIdx.y;
    const int b = bh >> 3, h = bh & 7;

    __shared__ __align__(16) u16 Kl[2][128 * 24];   // key rows x 16 d, padded to 48 B
    __shared__ __align__(16) u16 Vl[2][16 * 128];   // d rows x 128 keys, chunk-swizzled
    __shared__ __align__(16) u16 Pl[64 * 136];      // q rows x 128 keys

    const int tid = threadIdx.x;
    const int wave = tid >> 6, lane = tid & 63;
    const int l16 = lane & 15, quad = lane >> 4;
    const float LOG2E = 1.44269504088896340736f;

    // K staging (manual, padded rows): thread covers 16 B of one key row
    const u16* kgp = Kbf + ((size_t)bh * C_ + (tid >> 1)) * 16 + (tid & 1) * 8;
    const int kofs = (tid >> 1) * 24 + (tid & 1) * 8;
    // V staging via global_load_lds: lane: d = wave*4 + (lane>>4), chunk = lane&15 (swizzled source)
    const int vd = wave * 4 + (lane >> 4);
    const u16* vgp = Vbf + ((size_t)bh * 16 + vd) * C_ + (size_t)(((lane & 15) ^ (vd & 7)) * 8);
    const int vofs = wave * 4 * 128;

    // Q fragment (A-layout): m = lane&15, k(d) = quad*8+j ; d>=16 zero padding.
    s16x8 qf = {};
    if (quad < 2) {
        const u16* qp = qb + ((size_t)(b * C_ + q0 + wave * 16 + l16)) * DM_ + h * 16 + quad * 8;
        qf = *(const s16x8*)qp;
    }
    f32x4 o = (f32x4){0.f, 0.f, 0.f, 0.f};
    float mr[4] = {-3e38f, -3e38f, -3e38f, -3e38f};
    float lr[4] = {0.f, 0.f, 0.f, 0.f};

    // prologue: stage tile 0 into buffer 0
    {
        uint4 kv = *(const uint4*)(kgp);
        *(uint4*)&Kl[0][kofs] = kv;
        gl2lds16(vgp, &Vl[0][vofs]);
    }
    __syncthreads();   // drains reg-load/ds_write lgkm + gl2lds vmcnt, publishes tile 0

    for (int kt = 0; kt < 16; ++kt) {
        const int cur = kt & 1;
        const bool pre = (kt < 15);
        // issue stage(kt+1): K to regs (write to LDS later), V via LDS-DMA.
        // Buffers [cur^1] were last read at iteration kt-1, before the barrier.
        uint4 kvn = {};
        if (pre) {
            kvn = *(const uint4*)(kgp + (size_t)(kt + 1) * 128 * 16);
            gl2lds16(vgp + (size_t)(kt + 1) * 128, &Vl[cur ^ 1][vofs]);
        }

        // S = Q K^T : 8 N-frags of 16 keys (Kl[cur] published at last barrier)
        f32x4 sf[8];
#pragma unroll
        for (int fn = 0; fn < 8; ++fn) {
            s16x8 kb = {};
            if (quad < 2) kb = *(const s16x8*)&Kl[cur][(fn * 16 + l16) * 24 + quad * 8];
            sf[fn] = __builtin_amdgcn_mfma_f32_16x16x32_bf16(qf, kb, (f32x4){0.f, 0.f, 0.f, 0.f}, 0, 0, 0);
        }

        // online softmax: lane holds rows quad*4+r, cols l16 + 16*fn
        float mt[4];
#pragma unroll
        for (int r = 0; r < 4; ++r) {
            float m = sf[0][r];
#pragma unroll
            for (int fn = 1; fn < 8; ++fn) m = fmaxf(m, sf[fn][r]);
            m = fmaxf(m, __shfl_xor(m, 1));
            m = fmaxf(m, __shfl_xor(m, 2));
            m = fmaxf(m, __shfl_xor(m, 4));
            m = fmaxf(m, __shfl_xor(m, 8));
            mt[r] = m;
        }
        float al[4], ps[4];
#pragma unroll
        for (int r = 0; r < 4; ++r) {
            float mnew = fmaxf(mr[r], mt[r]);
            al[r] = fexp2((mr[r] - mnew) * LOG2E);
            mr[r] = mnew;
            ps[r] = 0.f;
        }
#pragma unroll
        for (int fn = 0; fn < 8; ++fn) {
#pragma unroll
            for (int r = 0; r < 4; ++r) {
                float p = fexp2((sf[fn][r] - mr[r]) * LOG2E);
                ps[r] += p;
                Pl[(wave * 16 + quad * 4 + r) * 136 + fn * 16 + l16] = f2bf(p);
            }
        }
        // write next K tile into LDS (load latency hidden under softmax)
        if (pre) *(uint4*)&Kl[cur ^ 1][kofs] = kvn;
#pragma unroll
        for (int r = 0; r < 4; ++r) {
            float t = ps[r];
            t += __shfl_xor(t, 1);
            t += __shfl_xor(t, 2);
            t += __shfl_xor(t, 4);
            t += __shfl_xor(t, 8);
            lr[r] = lr[r] * al[r] + t;
            o[r] *= al[r];
        }
        // Pl region is wave-private: same-wave ds_write -> ds_read needs no barrier.
        // O += P V  (K-dim = 128 keys, 4 MFMAs)
#pragma unroll
        for (int ko = 0; ko < 4; ++ko) {
            s16x8 pa = *(const s16x8*)&Pl[(wave * 16 + l16) * 136 + ko * 32 + quad * 8];
            s16x8 vb = *(const s16x8*)&Vl[cur][l16 * 128 + (((ko * 4 + quad) ^ (l16 & 7)) * 8)];
            o = __builtin_amdgcn_mfma_f32_16x16x32_bf16(pa, vb, o, 0, 0, 0);
        }
        // single barrier: drains my stage(kt+1) (vmcnt + lgkm) and publishes it
        __syncthreads();
    }

#pragma unroll
    for (int r = 0; r < 4; ++r) {
        float inv = 1.0f / lr[r];
        int row = q0 + wave * 16 + quad * 4 + r;
        att[((size_t)(b * C_ + row)) * DM_ + h * 16 + l16] = f2bf(o[r] * inv);
    }
}

// ---------------------------------------------------------------- final linear: out = att @ lw^T + lb
__global__ __launch_bounds__(256, 2) void lin_k(
        const u16* __restrict__ att, const float* __restrict__ lw,
        const float* __restrict__ lb, float* __restrict__ out) {
    const int r0 = blockIdx.x * 32;
    __shared__ __align__(16) u16 Wl[128 * 136];
    __shared__ __align__(16) u16 Atl[32 * 136];
    const int tid = threadIdx.x;
    const int wave = tid >> 6, lane = tid & 63;
    const int l16 = lane & 15, quad = lane >> 4;

    {   // stage lin_w -> bf16, layout Wl[j][i]
        int j = tid >> 1, half = tid & 1;
        const float* src = lw + (size_t)j * DM_ + half * 64;
        u16* dstp = &Wl[j * 136 + half * 64];
#pragma unroll
        for (int c = 0; c < 8; ++c) {
            float4 f0 = *(const float4*)(src + c * 8);
            float4 f1 = *(const float4*)(src + c * 8 + 4);
            uint4 p;
            p.x = pk2(f0.x, f0.y); p.y = pk2(f0.z, f0.w);
            p.z = pk2(f1.x, f1.y); p.w = pk2(f1.z, f1.w);
            *(uint4*)(dstp + c * 8) = p;
        }
    }
    {   // stage att tile
        int row = tid >> 3, seg = tid & 7;
        const uint4* src = (const uint4*)(att + ((size_t)(r0 + row)) * DM_ + seg * 16);
        uint4 a0 = src[0], a1 = src[1];
        *(uint4*)&Atl[row * 136 + seg * 16]     = a0;
        *(uint4*)&Atl[row * 136 + seg * 16 + 8] = a1;
    }
    __syncthreads();

    const int wn0 = wave * 32;
    f32x4 acc[2][2];
#pragma unroll
    for (int i = 0; i < 2; ++i)
#pragma unroll
        for (int j = 0; j < 2; ++j) acc[i][j] = (f32x4){0.f, 0.f, 0.f, 0.f};
#pragma unroll
    for (int ko = 0; ko < 4; ++ko) {
        s16x8 af[2], bf[2];
#pragma unroll
        for (int fm = 0; fm < 2; ++fm)
            af[fm] = *(const s16x8*)&Atl[(fm * 16 + l16) * 136 + ko * 32 + quad * 8];
#pragma unroll
        for (int fn = 0; fn < 2; ++fn)
            bf[fn] = *(const s16x8*)&Wl[(wn0 + fn * 16 + l16) * 136 + ko * 32 + quad * 8];
#pragma unroll
        for (int fm = 0; fm < 2; ++fm)
#pragma unroll
            for (int fn = 0; fn < 2; ++fn)
                acc[fm][fn] = __builtin_amdgcn_mfma_f32_16x16x32_bf16(af[fm], bf[fn], acc[fm][fn], 0, 0, 0);
    }
#pragma unroll
    for (int fm = 0; fm < 2; ++fm) {
#pragma unroll
        for (int fn = 0; fn < 2; ++fn) {
            int col = wn0 + fn * 16 + l16;
            float bias = lb[col];
#pragma unroll
            for (int r = 0; r < 4; ++r) {
                int row = r0 + fm * 16 + quad * 4 + r;
                out[(size_t)row * DM_ + col] = acc[fm][fn][r] + bias;
            }
        }
    }
}

// ---------------------------------------------------------------- launcher
extern "C" void kernel_launch(void* const* d_in, const int* in_sizes, int n_in,
                              void* d_out, int out_size, void* d_ws, size_t ws_size,
                              hipStream_t stream) {
    const float* query = (const float*)d_in[0];
    const float* key   = (const float*)d_in[1];
    const float* value = (const float*)d_in[2];
    const float* wk    = (const float*)d_in[3];
    const float* bk    = (const float*)d_in[4];
    const float* wv    = (const float*)d_in[5];
    const float* bv    = (const float*)d_in[6];
    const float* lw    = (const float*)d_in[7];
    const float* lb    = (const float*)d_in[8];
    float* out = (float*)d_out;

    char* ws = (char*)d_ws;
    u16*   bimt_k = (u16*)(ws);                       // 14,680,064 B
    u16*   bimt_v = (u16*)(ws + 14680064);            // 14,680,064 B (end 29,360,128)
    u16*   qbf    = (u16*)(ws + 29360128);            // 2 MB
    u16*   att    = (u16*)(ws + 31457280);            // 2 MB
    u16*   kbf    = (u16*)(ws + 33554432);            // 2 MB
    u16*   vbf    = (u16*)(ws + 35651584);            // 2 MB (end 37,748,736)
    float* ypk    = (float*)(ws + 37748736);          // 8 x 4 MB = 32 MB
    float* ypv    = (float*)(ws + 71303168);          // 8 x 4 MB = 32 MB (end ~100 MB)

    // 1) im2col^T bf16 for key & value
    prep_bimt<<<dim3(2048, 1, 2), 256, 0, stream>>>(key, value, bimt_k, bimt_v);
    // 2) query -> bf16 * 0.25
    prep_q<<<1024, 256, 0, stream>>>((const float4*)query, (uint2*)qbf);
    // 3) both convs as split-K GEMM -> private fp32 partials (no atomics, no zero-init)
    conv_gemm<<<dim3(16, 2, 16), 256, 0, stream>>>(wk, wv, bimt_k, bimt_v, ypk, ypv);
    // 4) sum partials + bias + bf16 + transpose prep for attention K/V (coalesced reads)
    kv_prep<<<1024, 256, 0, stream>>>(ypk, ypv, bk, bv, kbf, vbf);
    // 5) flash attention (single-barrier double-buffered staging)
    attn_k<<<dim3(32, 32), 256, 0, stream>>>(kbf, vbf, qbf, att);
    // 6) output projection
    lin_k<<<256, 256, 0, stream>>>(att, lw, lb, out);
}